// Round 13
// baseline (254.482 us; speedup 1.0000x reference)
//
#include <hip/hip_runtime.h>

#define N_NODES 10000
#define E_LOCAL 320000
#define E_GLOBAL 640000
#define CNT_LEN 10240   // padded node range (160 buckets x 64)
#define NB 160          // buckets per layer (64 node-ids each)
#define BCAP1 3072      // local bucket capacity  (mean 1280)
#define BCAP2 5632      // global bucket capacity (mean 2560)
#define CHUNK 2048      // edges per bucketize workgroup
#define NWG_L 157       // ceil(E_LOCAL/CHUNK)
#define NWG_G 313       // ceil(E_GLOBAL/CHUNK)

typedef __attribute__((ext_vector_type(8))) short short8;
typedef __attribute__((ext_vector_type(4))) float f32x4;
typedef __attribute__((ext_vector_type(4))) unsigned short ushort4v;
typedef __attribute__((ext_vector_type(2))) unsigned int uint2v;
typedef __attribute__((ext_vector_type(4))) unsigned int uint4v;

typedef __attribute__((address_space(1))) const void* gas_ptr;
typedef __attribute__((address_space(3))) void* lds_ptr;

__device__ __forceinline__ unsigned short f2bf(float f) {
  union { unsigned int i; float f; } v; v.f = f;
  unsigned int r = (v.i + 0x7FFF + ((v.i >> 16) & 1)) >> 16;
  return (unsigned short)r;
}
__device__ __forceinline__ void gld_lds16(const void* g, void* l) {
  __builtin_amdgcn_global_load_lds((gas_ptr)g, (lds_ptr)l, 16, 0, 0);
}

template<int NW> struct WVecT;
template<> struct WVecT<4> { using T = uint4v; };
template<> struct WVecT<2> { using T = uint2v; };

// word (2 bf16) -> 2 floats
template<int NW, typename WV>
__device__ __forceinline__ void w2f(WV w, float* f) {
  #pragma unroll
  for (int i = 0; i < NW; ++i) {
    union { unsigned int u; float x; } lo, hi;
    lo.u = w[i] << 16; hi.u = w[i] & 0xffff0000u;
    f[2 * i] = lo.x; f[2 * i + 1] = hi.x;
  }
}

// DPP butterfly add: full 16-lane sum in 4 VALU ops
template<int CTRL>
__device__ __forceinline__ float dppadd(float v) {
  int s = __builtin_amdgcn_update_dpp(0, __float_as_int(v), CTRL, 0xf, 0xf, true);
  return v + __int_as_float(s);
}
__device__ __forceinline__ float red16(float v) {
  v = dppadd<0xB1>(v);    // quad_perm [1,0,3,2]
  v = dppadd<0x4E>(v);    // quad_perm [2,3,0,1]
  v = dppadd<0x140>(v);   // row_mirror
  v = dppadd<0x141>(v);   // row_half_mirror
  return v;
}

// ---------------- prep: x->bf16, weight transposes, bias concat, bcur zero ----------------
__global__ __launch_bounds__(256) void prep(
    const float* __restrict__ x,
    const float* __restrict__ Wl1, const float* __restrict__ Wr1,
    const float* __restrict__ Wl2, const float* __restrict__ Wr2,
    const float* __restrict__ Wfc,
    const float* __restrict__ bl1, const float* __restrict__ br1,
    const float* __restrict__ bl2, const float* __restrict__ br2,
    ushort* __restrict__ xb, ushort* __restrict__ wt_all,
    ushort* __restrict__ wtfc, float* __restrict__ bias_all,
    int* __restrict__ bcur) {
  __shared__ float tl[32][33];
  int b = blockIdx.x;
  const int tid = threadIdx.x;
  if (b < 1250) {
    int i = b * 256 + tid;
    if (i < 320000) {
      float4 f = reinterpret_cast<const float4*>(x)[i];
      ushort4v o; o[0] = f2bf(f.x); o[1] = f2bf(f.y); o[2] = f2bf(f.z); o[3] = f2bf(f.w);
      reinterpret_cast<ushort4v*>(xb)[i] = o;
    }
    return;
  }
  b -= 1250;
  if (b < 288) {
    const float* W; ushort* dst; int N, nOff, ldK; int t = b;
    if (t < 64)       { W = Wl1; dst = wt_all; N = 512; nOff = 0;    ldK = 128; }
    else if (t < 128) { W = Wr1; dst = wt_all; N = 512; nOff = 512;  ldK = 128; t -= 64; }
    else if (t < 160) { W = Wl2; dst = wt_all; N = 256; nOff = 1024; ldK = 128; t -= 128; }
    else if (t < 192) { W = Wr2; dst = wt_all; N = 256; nOff = 1280; ldK = 128; t -= 160; }
    else              { W = Wfc; dst = wtfc;   N = 128; nOff = 0;    ldK = 768; t -= 192; }
    const int ntn = N / 32;
    const int n0 = (t % ntn) * 32, k0 = (t / ntn) * 32;
    const int tx = tid & 31, ty = tid >> 5;
    #pragma unroll
    for (int j = 0; j < 4; ++j)
      tl[ty + j * 8][tx] = W[(size_t)(k0 + ty + j * 8) * N + n0 + tx];
    __syncthreads();
    #pragma unroll
    for (int j = 0; j < 4; ++j)
      dst[(size_t)(nOff + n0 + ty + j * 8) * ldK + k0 + tx] = f2bf(tl[tx][ty + j * 8]);
    return;
  }
  for (int i = tid; i < 1536; i += 256) {
    float v = i < 512 ? bl1[i] : i < 1024 ? br1[i - 512]
            : i < 1280 ? bl2[i - 1024] : br2[i - 1280];
    bias_all[i] = v;
  }
  for (int i = tid; i < 2 * NB; i += 256) bcur[i] = 0;
}

// ---------------- MFMA GEMM: out[M,N] = A[M,K] @ Bt[N,K]^T (+bias) ----------------
template<bool OUT_BF16, int K>
__global__ __launch_bounds__(256) void gemm_mfma(
    const ushort* __restrict__ A, const ushort* __restrict__ Bt,
    const float* __restrict__ bias, void* __restrict__ outv,
    int M, int N, int ldOut) {
  __shared__ ushort As[2][64 * 32];
  __shared__ ushort Bs[2][64 * 32];
  const int tid  = threadIdx.x;
  const int wave = tid >> 6;
  const int lane = tid & 63;
  const int row0 = blockIdx.y * 64;
  const int col0 = blockIdx.x * 64;
  const int srow = tid >> 2;
  const int schunk = tid & 3;
  int ar = row0 + srow; if (ar >= M) ar = M - 1;
  const ushort* aSrc = A  + (size_t)ar * K + schunk * 8;
  const ushort* bSrc = Bt + (size_t)(col0 + srow) * K + schunk * 8;
  const int ldsOff = tid * 8;
  const int fr = lane & 15;
  const int kc = lane >> 4;

  f32x4 c[4];
  #pragma unroll
  for (int f = 0; f < 4; ++f) { c[f][0] = 0.f; c[f][1] = 0.f; c[f][2] = 0.f; c[f][3] = 0.f; }

  constexpr int NK = K / 32;
  gld_lds16(aSrc, &As[0][ldsOff]);
  gld_lds16(bSrc, &Bs[0][ldsOff]);
  #pragma unroll
  for (int kk = 0; kk < NK; ++kk) {
    const int cur = kk & 1;
    __syncthreads();
    if (kk + 1 < NK) {
      gld_lds16(aSrc + (kk + 1) * 32, &As[cur ^ 1][ldsOff]);
      gld_lds16(bSrc + (kk + 1) * 32, &Bs[cur ^ 1][ldsOff]);
    }
    short8 a = *reinterpret_cast<const short8*>(&As[cur][(wave * 16 + fr) * 32 + kc * 8]);
    #pragma unroll
    for (int f = 0; f < 4; ++f) {
      short8 b = *reinterpret_cast<const short8*>(&Bs[cur][(f * 16 + fr) * 32 + kc * 8]);
      c[f] = __builtin_amdgcn_mfma_f32_16x16x32_bf16(a, b, c[f], 0, 0, 0);
    }
  }
  const int orow = row0 + wave * 16 + (lane >> 4) * 4;
  #pragma unroll
  for (int f = 0; f < 4; ++f) {
    const int col = col0 + f * 16 + fr;
    const float bv = bias ? bias[col] : 0.f;
    #pragma unroll
    for (int q = 0; q < 4; ++q) {
      const int r = orow + q;
      if (r < M) {
        float v = c[f][q] + bv;
        if (OUT_BF16) ((ushort*)outv)[(size_t)r * ldOut + col] = f2bf(v);
        else          ((float*) outv)[(size_t)r * ldOut + col] = v;
      }
    }
  }
}

// ---------------- bucketed CSR build ----------------
__global__ __launch_bounds__(256) void bucketize(
    const int* __restrict__ sl, const int* __restrict__ dl,
    const int* __restrict__ sg, const int* __restrict__ dg,
    int* __restrict__ bcur, uint2* __restrict__ bb1, uint2* __restrict__ bb2) {
  __shared__ int h[NB];
  __shared__ int cur[NB];
  const int tid = threadIdx.x;
  int wg = blockIdx.x;
  const int* S; const int* D; int E0, Etot; uint2* BB; int* BC; int cap;
  if (wg < NWG_L) { S = sl; D = dl; E0 = wg * CHUNK; Etot = E_LOCAL;  BB = bb1; BC = bcur;      cap = BCAP1; }
  else { wg -= NWG_L; S = sg; D = dg; E0 = wg * CHUNK; Etot = E_GLOBAL; BB = bb2; BC = bcur + NB; cap = BCAP2; }
  for (int i = tid; i < NB; i += 256) h[i] = 0;
  __syncthreads();
  int myd[8], mys[8];
  #pragma unroll
  for (int k = 0; k < 8; ++k) {
    int e = E0 + k * 256 + tid;
    if (e < Etot) { myd[k] = D[e]; mys[k] = S[e]; atomicAdd(&h[myd[k] >> 6], 1); }
    else myd[k] = -1;
  }
  __syncthreads();
  for (int b = tid; b < NB; b += 256)
    cur[b] = h[b] ? atomicAdd(&BC[b], h[b]) : 0;
  __syncthreads();
  #pragma unroll
  for (int k = 0; k < 8; ++k) {
    if (myd[k] >= 0) {
      int b = myd[k] >> 6;
      int pos = atomicAdd(&cur[b], 1);
      if (pos < cap) BB[(size_t)b * cap + pos] = make_uint2((unsigned)mys[k], (unsigned)myd[k]);
    }
  }
}

__global__ __launch_bounds__(320) void scanb(const int* __restrict__ bcur,
                                             int* __restrict__ base) {
  __shared__ int v[2 * NB];
  __shared__ int sz[2 * NB];
  const int t = threadIdx.x;
  const int ls = (t < NB) ? 0 : NB;
  int s = min(bcur[t], (t < NB) ? BCAP1 : BCAP2);
  sz[t] = s; v[t] = s;
  __syncthreads();
  for (int o = 1; o < NB; o <<= 1) {
    int add = (t - o >= ls) ? v[t - o] : 0;
    __syncthreads();
    v[t] += add;
    __syncthreads();
  }
  base[t] = v[t] - sz[t];
}

__global__ __launch_bounds__(256) void csrbuild(
    const int* __restrict__ bcur, const int* __restrict__ base,
    const uint2* __restrict__ bb1, const uint2* __restrict__ bb2,
    int* __restrict__ csr1, int* __restrict__ csr2,
    int* __restrict__ off1, int* __restrict__ off2) {
  __shared__ int nh[64];
  __shared__ int ncur[64];
  const int tid = threadIdx.x;
  const int b = blockIdx.x;
  const uint2* BB; int* csr; int* off; int cap; int bi;
  if (b < NB) { BB = bb1; csr = csr1; off = off1; cap = BCAP1; bi = b; }
  else        { BB = bb2; csr = csr2; off = off2; cap = BCAP2; bi = b - NB; }
  const int n = min(bcur[b], cap);
  const uint2* P = BB + (size_t)bi * cap;
  if (tid < 64) nh[tid] = 0;
  __syncthreads();
  for (int i = tid; i < n; i += 256) atomicAdd(&nh[P[i].y & 63], 1);
  __syncthreads();
  if (tid == 0) {
    int s = base[b];
    #pragma unroll 4
    for (int j = 0; j < 64; ++j) { int c = nh[j]; nh[j] = s; s += c; }
  }
  __syncthreads();
  if (tid < 64) { off[bi * 64 + tid] = nh[tid]; ncur[tid] = nh[tid]; }
  __syncthreads();
  for (int i = tid; i < n; i += 256) {
    uint2 p = P[i];
    int pos = atomicAdd(&ncur[p.y & 63], 1);
    csr[pos] = (int)p.x;
  }
}

// ---------------- Cooperative 4-wave-per-node aggregation ----------------
template<int H, int U>
__device__ __forceinline__ void agg_block(
    const ushort* __restrict__ xl, const ushort* __restrict__ xr,
    const float* __restrict__ att, const int* __restrict__ csr,
    const int* __restrict__ off, const float* __restrict__ bias,
    int inLd, ushort* __restrict__ outp, int outLd, int node,
    float* __restrict__ sacc, float* __restrict__ sden) {
  constexpr int TC = H * 128;
  constexpr int PER = TC / 64;
  constexpr int NW = PER / 2;
  constexpr int GRP = 64 / H;
  using WVec = typename WVecT<NW>::T;
  const int tid = threadIdx.x;
  const int wave = tid >> 6;
  const int lane = tid & 63;
  const int base = lane * PER;
  const int head = lane / GRP;

  float attv[PER], xri[PER], acc[PER];
  #pragma unroll
  for (int p = 0; p < PER; ++p) attv[p] = att[base + p] * 1.4426950408889634f;  // log2(e)
  {
    WVec r = *reinterpret_cast<const WVec*>(&xr[(size_t)node * inLd + base]);
    w2f<NW>(r, xri);
  }
  #pragma unroll
  for (int p = 0; p < PER; ++p) acc[p] = 0.f;
  float den = 0.f;

  const int e0n = off[node], e1n = off[node + 1];
  const int chunk = (e1n - e0n + 3) >> 2;
  const int e0 = e0n + wave * chunk;
  const int e1 = min(e0 + chunk, e1n);

  if (wave == 0) {   // self-loop message
    WVec r = *reinterpret_cast<const WVec*>(&xl[(size_t)node * inLd + base]);
    float xs[PER]; w2f<NW>(r, xs);
    float d = 0.f;
    #pragma unroll
    for (int p = 0; p < PER; ++p) {
      float t = xs[p] + xri[p];
      t = fmaxf(t, 0.2f * t);
      d = fmaf(t, attv[p], d);
    }
    d = red16(d);
    if (GRP == 32) d += __shfl_xor(d, 16, 64);
    float wgt = exp2f(d);
    den = wgt;
    #pragma unroll
    for (int p = 0; p < PER; ++p) acc[p] = wgt * xs[p];
  }

  auto loadIdx = [&](int bb, int* ii) {
    #pragma unroll
    for (int m = 0; m < U; ++m) ii[m] = csr[e0 + bb * U + m];
  };
  auto loadRows = [&](const int* ii, WVec* rr) {
    #pragma unroll
    for (int m = 0; m < U; ++m)
      rr[m] = *reinterpret_cast<const WVec*>(&xl[(size_t)ii[m] * inLd + base]);
  };
  auto computeB = [&](WVec* rr) {
    float pp[U]; float xs[U][PER];
    #pragma unroll
    for (int m = 0; m < U; ++m) {
      w2f<NW>(rr[m], xs[m]);
      float d = 0.f;
      #pragma unroll
      for (int p = 0; p < PER; ++p) {
        float t = xs[m][p] + xri[p];
        t = fmaxf(t, 0.2f * t);
        d = fmaf(t, attv[p], d);
      }
      pp[m] = d;
    }
    #pragma unroll
    for (int m = 0; m < U; ++m) pp[m] = red16(pp[m]);
    if (GRP == 32) {
      #pragma unroll
      for (int m = 0; m < U; ++m) pp[m] += __shfl_xor(pp[m], 16, 64);
    }
    #pragma unroll
    for (int m = 0; m < U; ++m) {
      float wgt = exp2f(pp[m]);
      den += wgt;
      #pragma unroll
      for (int p = 0; p < PER; ++p) acc[p] = fmaf(wgt, xs[m][p], acc[p]);
    }
  };

  const int nb = (e1 - e0) / U;
  WVec rA[U], rB[U];
  int iA[U], iB[U];
  if (nb > 0) { loadIdx(0, iA); loadRows(iA, rA); }
  if (nb > 1) loadIdx(1, iB);
  int b = 0;
  for (; b + 2 <= nb; b += 2) {           // copy-free ping-pong
    loadRows(iB, rB);
    if (b + 2 < nb) loadIdx(b + 2, iA);
    computeB(rA);
    if (b + 2 < nb) loadRows(iA, rA);
    if (b + 3 < nb) loadIdx(b + 3, iB);
    computeB(rB);
  }
  if (b < nb) computeB(rA);
  for (int e = e0 + nb * U; e < e1; ++e) {  // remainder singles
    int s = csr[e];
    WVec r = *reinterpret_cast<const WVec*>(&xl[(size_t)s * inLd + base]);
    float xs[PER]; w2f<NW>(r, xs);
    float d = 0.f;
    #pragma unroll
    for (int p = 0; p < PER; ++p) {
      float t = xs[p] + xri[p];
      t = fmaxf(t, 0.2f * t);
      d = fmaf(t, attv[p], d);
    }
    d = red16(d);
    if (GRP == 32) d += __shfl_xor(d, 16, 64);
    float wgt = exp2f(d);
    den += wgt;
    #pragma unroll
    for (int p = 0; p < PER; ++p) acc[p] = fmaf(wgt, xs[p], acc[p]);
  }

  // LDS combine across the 4 waves
  #pragma unroll
  for (int p = 0; p < PER; ++p) sacc[wave * TC + base + p] = acc[p];
  if ((lane & (GRP - 1)) == 0) sden[wave * H + head] = den;
  __syncthreads();
  constexpr int CH = TC / 256;
  #pragma unroll
  for (int j = 0; j < CH; ++j) {
    const int c = tid * CH + j;
    float s = sacc[c] + sacc[TC + c] + sacc[2 * TC + c] + sacc[3 * TC + c];
    const int h = c >> 7;
    float dt = sden[h] + sden[H + h] + sden[2 * H + h] + sden[3 * H + h];
    outp[(size_t)node * outLd + c] = f2bf(s / dt + bias[c]);
  }
}

__global__ __launch_bounds__(256) void aggregate2(
    const ushort* __restrict__ feat,
    const float* __restrict__ att1, const float* __restrict__ att2,
    const int* __restrict__ csr1, const int* __restrict__ off1,
    const float* __restrict__ b1,
    const int* __restrict__ csr2, const int* __restrict__ off2,
    const float* __restrict__ b2,
    ushort* __restrict__ hb) {
  __shared__ float sacc[4 * 512];
  __shared__ float sden[16];
  const int nd = blockIdx.x;
  if (nd < N_NODES)
    agg_block<4, 3>(feat, feat + 512, att1, csr1, off1, b1, 1536, hb, 768,
                    nd, sacc, sden);
  else
    agg_block<2, 4>(feat + 1024, feat + 1280, att2, csr2, off2, b2, 1536,
                    hb + 512, 768, nd - N_NODES, sacc, sden);
}

extern "C" void kernel_launch(void* const* d_in, const int* in_sizes, int n_in,
                              void* d_out, int out_size, void* d_ws, size_t ws_size,
                              hipStream_t stream) {
  const float* x    = (const float*)d_in[0];
  const int*   ei   = (const int*)d_in[1];
  const int*   gei  = (const int*)d_in[2];
  const float* Wl1  = (const float*)d_in[3];
  const float* bl1  = (const float*)d_in[4];
  const float* Wr1  = (const float*)d_in[5];
  const float* br1  = (const float*)d_in[6];
  const float* att1 = (const float*)d_in[7];
  const float* b1   = (const float*)d_in[8];
  const float* Wl2  = (const float*)d_in[9];
  const float* bl2  = (const float*)d_in[10];
  const float* Wr2  = (const float*)d_in[11];
  const float* br2  = (const float*)d_in[12];
  const float* att2 = (const float*)d_in[13];
  const float* b2   = (const float*)d_in[14];
  const float* Wfc  = (const float*)d_in[15];
  const float* bfc  = (const float*)d_in[16];
  float* out = (float*)d_out;

  char* w = (char*)d_ws;
  ushort* xb     = (ushort*)w; w += (size_t)N_NODES * 128 * 2;
  ushort* feat   = (ushort*)w; w += (size_t)N_NODES * 1536 * 2;
  ushort* hb     = (ushort*)w; w += (size_t)N_NODES * 768 * 2;
  ushort* wt_all = (ushort*)w; w += (size_t)1536 * 128 * 2;
  ushort* wtfc   = (ushort*)w; w += (size_t)128 * 768 * 2;
  float* bias_all = (float*)w; w += 1536 * 4;
  int* off1 = (int*)w;            w += (size_t)CNT_LEN * 4;
  int* off2 = (int*)w;            w += (size_t)CNT_LEN * 4;
  int* csr1 = (int*)w;            w += (size_t)E_LOCAL * 4;
  int* csr2 = (int*)w;            w += (size_t)E_GLOBAL * 4;
  int* bcur = (int*)w;            w += 2 * NB * 4;
  int* bbase = (int*)w;           w += 2 * NB * 4;
  uint2* bb1 = (uint2*)w;         w += (size_t)NB * BCAP1 * 8;
  uint2* bb2 = (uint2*)w;         w += (size_t)NB * BCAP2 * 8;

  const int N = N_NODES;
  prep<<<1539, 256, 0, stream>>>(x, Wl1, Wr1, Wl2, Wr2, Wfc,
                                 bl1, br1, bl2, br2,
                                 xb, wt_all, wtfc, bias_all, bcur);

  bucketize<<<NWG_L + NWG_G, 256, 0, stream>>>(
      ei, ei + E_LOCAL, gei, gei + E_GLOBAL, bcur, bb1, bb2);
  scanb<<<1, 320, 0, stream>>>(bcur, bbase);
  csrbuild<<<2 * NB, 256, 0, stream>>>(bcur, bbase, bb1, bb2,
                                       csr1, csr2, off1, off2);

  gemm_mfma<true, 128><<<dim3(24, 157), 256, 0, stream>>>(
      xb, wt_all, bias_all, feat, N, 1536, 1536);

  // Cooperative aggregation, both layers in one dispatch
  aggregate2<<<2 * N, 256, 0, stream>>>(feat, att1, att2,
                                        csr1, off1, b1, csr2, off2, b2, hb);

  gemm_mfma<false, 768><<<dim3(2, 157), 256, 0, stream>>>(hb, wtfc, bfc, out, N, 128, 128);
}

// Round 16
// 252.216 us; speedup vs baseline: 1.0090x; 1.0090x over previous
//
#include <hip/hip_runtime.h>

#define N_NODES 10000
#define E_LOCAL 320000
#define E_GLOBAL 640000
#define NB 160          // buckets per layer (64 node-ids each)
#define BCAP1 3072      // local bucket capacity  (mean 1280)
#define BCAP2 5632      // global bucket capacity (mean 2560)
#define CHUNK 2048      // edges per bucketize workgroup
#define NWG_L 157       // ceil(E_LOCAL/CHUNK)
#define NWG_G 313       // ceil(E_GLOBAL/CHUNK)
#define L2E 1.4426950408889634f

typedef __attribute__((ext_vector_type(8))) short short8;
typedef __attribute__((ext_vector_type(4))) float f32x4;
typedef __attribute__((ext_vector_type(2))) float float2v;
typedef __attribute__((ext_vector_type(4))) unsigned short ushort4v;
typedef __attribute__((ext_vector_type(2))) unsigned int uint2v;
typedef __attribute__((ext_vector_type(4))) unsigned int uint4v;

typedef __attribute__((address_space(1))) const void* gas_ptr;
typedef __attribute__((address_space(3))) void* lds_ptr;

__device__ __forceinline__ unsigned short f2bf(float f) {
  union { unsigned int i; float f; } v; v.f = f;
  unsigned int r = (v.i + 0x7FFF + ((v.i >> 16) & 1)) >> 16;
  return (unsigned short)r;
}
__device__ __forceinline__ void gld_lds16(const void* g, void* l) {
  __builtin_amdgcn_global_load_lds((gas_ptr)g, (lds_ptr)l, 16, 0, 0);
}
// one 32-bit word (2 bf16) -> float2
__device__ __forceinline__ float2v bf2x2(unsigned int w) {
  union { unsigned int u[2]; float2v f; } v;
  v.u[0] = w << 16; v.u[1] = w & 0xffff0000u;
  return v.f;
}

template<int NW> struct WVecT;
template<> struct WVecT<4> { using T = uint4v; };
template<> struct WVecT<2> { using T = uint2v; };

// DPP butterfly add: full 16-lane sum
template<int CTRL>
__device__ __forceinline__ float dppadd(float v) {
  int s = __builtin_amdgcn_update_dpp(0, __float_as_int(v), CTRL, 0xf, 0xf, true);
  return v + __int_as_float(s);
}
__device__ __forceinline__ float red16(float v) {
  v = dppadd<0xB1>(v);
  v = dppadd<0x4E>(v);
  v = dppadd<0x140>(v);
  v = dppadd<0x141>(v);
  return v;
}

// ================= K1: bucketize + prep (independent block ranges) =================
__device__ void bucketize_body(int wg, const int* sl, const int* dl,
    const int* sg, const int* dg, int* bcur, uint2* bb1, uint2* bb2) {
  __shared__ int h[NB];
  __shared__ int cur[NB];
  const int tid = threadIdx.x;
  const int* S; const int* D; int E0, Etot; uint2* BB; int* BC; int cap;
  if (wg < NWG_L) { S = sl; D = dl; E0 = wg * CHUNK; Etot = E_LOCAL;  BB = bb1; BC = bcur;      cap = BCAP1; }
  else { wg -= NWG_L; S = sg; D = dg; E0 = wg * CHUNK; Etot = E_GLOBAL; BB = bb2; BC = bcur + NB; cap = BCAP2; }
  for (int i = tid; i < NB; i += 256) h[i] = 0;
  __syncthreads();
  int myd[8], mys[8];
  #pragma unroll
  for (int k = 0; k < 8; ++k) {
    int e = E0 + k * 256 + tid;
    if (e < Etot) { myd[k] = D[e]; mys[k] = S[e]; atomicAdd(&h[myd[k] >> 6], 1); }
    else myd[k] = -1;
  }
  __syncthreads();
  for (int b = tid; b < NB; b += 256)
    cur[b] = h[b] ? atomicAdd(&BC[b], h[b]) : 0;
  __syncthreads();
  #pragma unroll
  for (int k = 0; k < 8; ++k) {
    if (myd[k] >= 0) {
      int b = myd[k] >> 6;
      int pos = atomicAdd(&cur[b], 1);
      if (pos < cap) BB[(size_t)b * cap + pos] = make_uint2((unsigned)mys[k], (unsigned)myd[k]);
    }
  }
}

__device__ void prep_body(int b,
    const float* x, const float* Wl1, const float* Wr1,
    const float* Wl2, const float* Wr2, const float* Wfc,
    const float* bl1, const float* br1, const float* bl2, const float* br2,
    ushort* xb, ushort* wt_all, ushort* wtfc, float* bias_all) {
  __shared__ float tl[32][33];
  const int tid = threadIdx.x;
  if (b < 1250) {
    int i = b * 256 + tid;
    if (i < 320000) {
      float4 f = reinterpret_cast<const float4*>(x)[i];
      ushort4v o; o[0] = f2bf(f.x); o[1] = f2bf(f.y); o[2] = f2bf(f.z); o[3] = f2bf(f.w);
      reinterpret_cast<ushort4v*>(xb)[i] = o;
    }
    return;
  }
  b -= 1250;
  if (b < 288) {
    const float* W; ushort* dst; int N, nOff, ldK; int t = b;
    if (t < 64)       { W = Wl1; dst = wt_all; N = 512; nOff = 0;    ldK = 128; }
    else if (t < 128) { W = Wr1; dst = wt_all; N = 512; nOff = 512;  ldK = 128; t -= 64; }
    else if (t < 160) { W = Wl2; dst = wt_all; N = 256; nOff = 1024; ldK = 128; t -= 128; }
    else if (t < 192) { W = Wr2; dst = wt_all; N = 256; nOff = 1280; ldK = 128; t -= 160; }
    else              { W = Wfc; dst = wtfc;   N = 128; nOff = 0;    ldK = 768; t -= 192; }
    const int ntn = N / 32;
    const int n0 = (t % ntn) * 32, k0 = (t / ntn) * 32;
    const int tx = tid & 31, ty = tid >> 5;
    #pragma unroll
    for (int j = 0; j < 4; ++j)
      tl[ty + j * 8][tx] = W[(size_t)(k0 + ty + j * 8) * N + n0 + tx];
    __syncthreads();
    #pragma unroll
    for (int j = 0; j < 4; ++j)
      dst[(size_t)(nOff + n0 + ty + j * 8) * ldK + k0 + tx] = f2bf(tl[tx][ty + j * 8]);
    return;
  }
  for (int i = tid; i < 1536; i += 256) {
    float v = i < 512 ? bl1[i] : i < 1024 ? br1[i - 512]
            : i < 1280 ? bl2[i - 1024] : br2[i - 1280];
    bias_all[i] = v;
  }
}

__global__ __launch_bounds__(256) void k1_prep_bucket(
    const int* ei, const int* gei,
    const float* x, const float* Wl1, const float* Wr1,
    const float* Wl2, const float* Wr2, const float* Wfc,
    const float* bl1, const float* br1, const float* bl2, const float* br2,
    ushort* xb, ushort* wt_all, ushort* wtfc, float* bias_all,
    int* bcur, uint2* bb1, uint2* bb2) {
  const int b = blockIdx.x;
  if (b < NWG_L + NWG_G)
    bucketize_body(b, ei, ei + E_LOCAL, gei, gei + E_GLOBAL, bcur, bb1, bb2);
  else
    prep_body(b - (NWG_L + NWG_G), x, Wl1, Wr1, Wl2, Wr2, Wfc,
              bl1, br1, bl2, br2, xb, wt_all, wtfc, bias_all);
}

// ================= K2: csrbuild (self-reserving) + transform GEMM =================
__device__ void csrbuild_body(int b, const int* bcur, int* gcur,
    const uint2* bb1, const uint2* bb2,
    int* csr1, int* csr2, int* st1, int* en1, int* st2, int* en2) {
  __shared__ int nh[64];
  __shared__ int ncur[64];
  __shared__ int sbase;
  const int tid = threadIdx.x;
  const uint2* BB; int* csr; int* st; int* en; int cap; int bi; int layer;
  if (b < NB) { BB = bb1; csr = csr1; st = st1; en = en1; cap = BCAP1; bi = b; layer = 0; }
  else        { BB = bb2; csr = csr2; st = st2; en = en2; cap = BCAP2; bi = b - NB; layer = 1; }
  const int n = min(bcur[b], cap);
  if (tid == 0) sbase = atomicAdd(&gcur[layer], n);
  if (tid < 64) nh[tid] = 0;
  __syncthreads();
  const uint2* P = BB + (size_t)bi * cap;
  for (int i = tid; i < n; i += 256) atomicAdd(&nh[P[i].y & 63], 1);
  __syncthreads();
  int cnt = (tid < 64) ? nh[tid] : 0;
  __syncthreads();
  if (tid == 0) {
    int s = sbase;
    #pragma unroll 4
    for (int j = 0; j < 64; ++j) { int c = nh[j]; nh[j] = s; s += c; }
  }
  __syncthreads();
  if (tid < 64) {
    st[bi * 64 + tid] = nh[tid];
    en[bi * 64 + tid] = nh[tid] + cnt;
    ncur[tid] = nh[tid];
  }
  __syncthreads();
  for (int i = tid; i < n; i += 256) {
    uint2 p = P[i];
    int pos = atomicAdd(&ncur[p.y & 63], 1);
    csr[pos] = (int)p.x;
  }
}

template<bool OUT_BF16, int K>
__device__ void gemm_body(int bx, int by,
    const ushort* __restrict__ A, const ushort* __restrict__ Bt,
    const float* __restrict__ bias, void* __restrict__ outv,
    int M, int N, int ldOut) {
  __shared__ ushort As[2][64 * 32];
  __shared__ ushort Bs[2][64 * 32];
  const int tid  = threadIdx.x;
  const int wave = tid >> 6;
  const int lane = tid & 63;
  const int row0 = by * 64;
  const int col0 = bx * 64;
  const int srow = tid >> 2;
  const int schunk = tid & 3;
  int ar = row0 + srow; if (ar >= M) ar = M - 1;
  const ushort* aSrc = A  + (size_t)ar * K + schunk * 8;
  const ushort* bSrc = Bt + (size_t)(col0 + srow) * K + schunk * 8;
  const int ldsOff = tid * 8;
  const int fr = lane & 15;
  const int kc = lane >> 4;

  f32x4 c[4];
  #pragma unroll
  for (int f = 0; f < 4; ++f) { c[f][0] = 0.f; c[f][1] = 0.f; c[f][2] = 0.f; c[f][3] = 0.f; }

  constexpr int NK = K / 32;
  gld_lds16(aSrc, &As[0][ldsOff]);
  gld_lds16(bSrc, &Bs[0][ldsOff]);
  #pragma unroll
  for (int kk = 0; kk < NK; ++kk) {
    const int cur = kk & 1;
    __syncthreads();
    if (kk + 1 < NK) {
      gld_lds16(aSrc + (kk + 1) * 32, &As[cur ^ 1][ldsOff]);
      gld_lds16(bSrc + (kk + 1) * 32, &Bs[cur ^ 1][ldsOff]);
    }
    short8 a = *reinterpret_cast<const short8*>(&As[cur][(wave * 16 + fr) * 32 + kc * 8]);
    #pragma unroll
    for (int f = 0; f < 4; ++f) {
      short8 b = *reinterpret_cast<const short8*>(&Bs[cur][(f * 16 + fr) * 32 + kc * 8]);
      c[f] = __builtin_amdgcn_mfma_f32_16x16x32_bf16(a, b, c[f], 0, 0, 0);
    }
  }
  const int orow = row0 + wave * 16 + (lane >> 4) * 4;
  #pragma unroll
  for (int f = 0; f < 4; ++f) {
    const int col = col0 + f * 16 + fr;
    const float bv = bias ? bias[col] : 0.f;
    #pragma unroll
    for (int q = 0; q < 4; ++q) {
      const int r = orow + q;
      if (r < M) {
        float v = c[f][q] + bv;
        if (OUT_BF16) ((ushort*)outv)[(size_t)r * ldOut + col] = f2bf(v);
        else          ((float*) outv)[(size_t)r * ldOut + col] = v;
      }
    }
  }
}

__global__ __launch_bounds__(256) void k2_csr_gemm(
    const int* bcur, int* gcur, const uint2* bb1, const uint2* bb2,
    int* csr1, int* csr2, int* st1, int* en1, int* st2, int* en2,
    const ushort* xb, const ushort* wt_all, const float* bias_all,
    ushort* feat) {
  const int b = blockIdx.x;
  if (b < 2 * NB) {
    csrbuild_body(b, bcur, gcur, bb1, bb2, csr1, csr2, st1, en1, st2, en2);
    return;
  }
  const int g = b - 2 * NB;
  gemm_body<true, 128>(g % 24, g / 24, xb, wt_all, bias_all, feat,
                       N_NODES, 1536, 1536);
}

__global__ __launch_bounds__(256) void k4_fc(
    const ushort* hb, const ushort* wtfc, const float* bfc, float* out) {
  gemm_body<false, 768>(blockIdx.x & 1, blockIdx.x >> 1, hb, wtfc, bfc, out,
                        N_NODES, 128, 128);
}

// ================= K3: cooperative 4-wave-per-node aggregation =================
// packed f32 math + SGPR-base gathers + LDS-staged xr row
template<int H, int U>
__device__ __forceinline__ void agg_block(
    const ushort* __restrict__ xl, const ushort* __restrict__ xr,
    const float* __restrict__ att, const int* __restrict__ csr,
    const int* __restrict__ st, const int* __restrict__ en,
    const float* __restrict__ bias, int inLd,
    ushort* __restrict__ outp, int outLd, int node,
    float* __restrict__ sacc, float* __restrict__ sden,
    ushort* __restrict__ srow) {
  constexpr int TC = H * 128;
  constexpr int PER = TC / 64;
  constexpr int NW = PER / 2;
  constexpr int GRP = 64 / H;
  using WVec = typename WVecT<NW>::T;
  const int tid = threadIdx.x;
  const int wave = tid >> 6;
  const int lane = tid & 63;
  const int base = lane * PER;
  const int head = lane / GRP;

  // stage node's xr row into LDS once per block
  {
    const ushort* xrrow = xr + (size_t)node * inLd;
    for (int i = tid; i < TC / 8; i += 256)
      *reinterpret_cast<short8*>(srow + i * 8) =
          *reinterpret_cast<const short8*>(xrrow + i * 8);
  }
  __syncthreads();

  float2v attv[NW], xri[NW], acc[NW];
  #pragma unroll
  for (int w = 0; w < NW; ++w) {
    attv[w][0] = att[base + 2 * w] * L2E;
    attv[w][1] = att[base + 2 * w + 1] * L2E;
    xri[w] = bf2x2(*reinterpret_cast<const unsigned int*>(srow + base + 2 * w));
    acc[w][0] = 0.f; acc[w][1] = 0.f;
  }
  float den = 0.f;

  const int e0n = st[node], e1n = en[node];
  const int chunk = (e1n - e0n + 3) >> 2;
  const int e0 = e0n + wave * chunk;
  const int e1 = min(e0 + chunk, e1n);

  if (wave == 0) {   // self-loop (node row; node is SGPR)
    const WVec r = *reinterpret_cast<const WVec*>(xl + (size_t)node * inLd + base);
    float2v d2 = {0.f, 0.f};
    float2v xs[NW];
    #pragma unroll
    for (int w = 0; w < NW; ++w) {
      xs[w] = bf2x2(r[w]);
      float2v t2 = xs[w] + xri[w];
      t2 = __builtin_elementwise_max(t2, t2 * 0.2f);
      d2 = __builtin_elementwise_fma(t2, attv[w], d2);
    }
    float d = red16(d2[0] + d2[1]);
    if (GRP == 32) d += __shfl_xor(d, 16, 64);
    float wgt = exp2f(d);
    den = wgt;
    float2v w2 = {wgt, wgt};
    #pragma unroll
    for (int w = 0; w < NW; ++w) acc[w] = __builtin_elementwise_fma(w2, xs[w], acc[w]);
  }

  auto loadIdx = [&](int bb, int* ii) {
    #pragma unroll
    for (int m = 0; m < U; ++m) ii[m] = csr[e0 + bb * U + m];
  };
  auto loadRows = [&](const int* ii, WVec* rr) {
    #pragma unroll
    for (int m = 0; m < U; ++m) {
      const int sv = __builtin_amdgcn_readfirstlane(ii[m]);   // SGPR base
      rr[m] = *reinterpret_cast<const WVec*>(xl + (size_t)sv * inLd + base);
    }
  };
  auto computeB = [&](WVec* rr) {
    float2v xs[U][NW];
    float pp[U];
    #pragma unroll
    for (int m = 0; m < U; ++m) {
      float2v d2 = {0.f, 0.f};
      #pragma unroll
      for (int w = 0; w < NW; ++w) {
        xs[m][w] = bf2x2(rr[m][w]);
        float2v t2 = xs[m][w] + xri[w];
        t2 = __builtin_elementwise_max(t2, t2 * 0.2f);
        d2 = __builtin_elementwise_fma(t2, attv[w], d2);
      }
      pp[m] = d2[0] + d2[1];
    }
    #pragma unroll
    for (int m = 0; m < U; ++m) pp[m] = red16(pp[m]);
    if (GRP == 32) {
      #pragma unroll
      for (int m = 0; m < U; ++m) pp[m] += __shfl_xor(pp[m], 16, 64);
    }
    #pragma unroll
    for (int m = 0; m < U; ++m) {
      float wgt = exp2f(pp[m]);
      den += wgt;
      float2v w2 = {wgt, wgt};
      #pragma unroll
      for (int w = 0; w < NW; ++w) acc[w] = __builtin_elementwise_fma(w2, xs[m][w], acc[w]);
    }
  };

  const int nb = (e1 - e0) / U;
  WVec rA[U], rB[U];
  int iA[U], iB[U];
  if (nb > 0) { loadIdx(0, iA); loadRows(iA, rA); }
  if (nb > 1) loadIdx(1, iB);
  int b = 0;
  for (; b + 2 <= nb; b += 2) {
    loadRows(iB, rB);
    if (b + 2 < nb) loadIdx(b + 2, iA);
    computeB(rA);
    if (b + 2 < nb) loadRows(iA, rA);
    if (b + 3 < nb) loadIdx(b + 3, iB);
    computeB(rB);
  }
  if (b < nb) computeB(rA);
  for (int e = e0 + nb * U; e < e1; ++e) {
    const int sv = __builtin_amdgcn_readfirstlane(csr[e]);
    const WVec r = *reinterpret_cast<const WVec*>(xl + (size_t)sv * inLd + base);
    float2v d2 = {0.f, 0.f};
    float2v xs[NW];
    #pragma unroll
    for (int w = 0; w < NW; ++w) {
      xs[w] = bf2x2(r[w]);
      float2v t2 = xs[w] + xri[w];
      t2 = __builtin_elementwise_max(t2, t2 * 0.2f);
      d2 = __builtin_elementwise_fma(t2, attv[w], d2);
    }
    float d = red16(d2[0] + d2[1]);
    if (GRP == 32) d += __shfl_xor(d, 16, 64);
    float wgt = exp2f(d);
    den += wgt;
    float2v w2 = {wgt, wgt};
    #pragma unroll
    for (int w = 0; w < NW; ++w) acc[w] = __builtin_elementwise_fma(w2, xs[w], acc[w]);
  }

  // LDS combine across the 4 waves
  #pragma unroll
  for (int w = 0; w < NW; ++w) {
    sacc[wave * TC + base + 2 * w]     = acc[w][0];
    sacc[wave * TC + base + 2 * w + 1] = acc[w][1];
  }
  if ((lane & (GRP - 1)) == 0) sden[wave * H + head] = den;
  __syncthreads();
  constexpr int CH = TC / 256;
  #pragma unroll
  for (int j = 0; j < CH; ++j) {
    const int c = tid * CH + j;
    float s = sacc[c] + sacc[TC + c] + sacc[2 * TC + c] + sacc[3 * TC + c];
    const int h = c >> 7;
    float dt = sden[h] + sden[H + h] + sden[2 * H + h] + sden[3 * H + h];
    outp[(size_t)node * outLd + c] = f2bf(s / dt + bias[c]);
  }
}

__global__ __launch_bounds__(256) void aggregate2(
    const ushort* __restrict__ feat,
    const float* __restrict__ att1, const float* __restrict__ att2,
    const int* __restrict__ csr1, const int* __restrict__ st1,
    const int* __restrict__ en1, const float* __restrict__ b1,
    const int* __restrict__ csr2, const int* __restrict__ st2,
    const int* __restrict__ en2, const float* __restrict__ b2,
    ushort* __restrict__ hb) {
  __shared__ float sacc[4 * 512];
  __shared__ float sden[16];
  __shared__ ushort srow[512];
  const int nd = blockIdx.x;
  if (nd < N_NODES)
    agg_block<4, 3>(feat, feat + 512, att1, csr1, st1, en1, b1, 1536, hb, 768,
                    nd, sacc, sden, srow);
  else
    agg_block<2, 4>(feat + 1024, feat + 1280, att2, csr2, st2, en2, b2, 1536,
                    hb + 512, 768, nd - N_NODES, sacc, sden, srow);
}

extern "C" void kernel_launch(void* const* d_in, const int* in_sizes, int n_in,
                              void* d_out, int out_size, void* d_ws, size_t ws_size,
                              hipStream_t stream) {
  const float* x    = (const float*)d_in[0];
  const int*   ei   = (const int*)d_in[1];
  const int*   gei  = (const int*)d_in[2];
  const float* Wl1  = (const float*)d_in[3];
  const float* bl1  = (const float*)d_in[4];
  const float* Wr1  = (const float*)d_in[5];
  const float* br1  = (const float*)d_in[6];
  const float* att1 = (const float*)d_in[7];
  const float* b1   = (const float*)d_in[8];
  const float* Wl2  = (const float*)d_in[9];
  const float* bl2  = (const float*)d_in[10];
  const float* Wr2  = (const float*)d_in[11];
  const float* br2  = (const float*)d_in[12];
  const float* att2 = (const float*)d_in[13];
  const float* b2   = (const float*)d_in[14];
  const float* Wfc  = (const float*)d_in[15];
  const float* bfc  = (const float*)d_in[16];
  float* out = (float*)d_out;

  char* w = (char*)d_ws;
  ushort* xb     = (ushort*)w; w += (size_t)N_NODES * 128 * 2;
  ushort* feat   = (ushort*)w; w += (size_t)N_NODES * 1536 * 2;
  ushort* hb     = (ushort*)w; w += (size_t)N_NODES * 768 * 2;
  ushort* wt_all = (ushort*)w; w += (size_t)1536 * 128 * 2;
  ushort* wtfc   = (ushort*)w; w += (size_t)128 * 768 * 2;
  float* bias_all = (float*)w; w += 1536 * 4;
  int* st1 = (int*)w;             w += (size_t)10240 * 4;
  int* en1 = (int*)w;             w += (size_t)10240 * 4;
  int* st2 = (int*)w;             w += (size_t)10240 * 4;
  int* en2 = (int*)w;             w += (size_t)10240 * 4;
  int* csr1 = (int*)w;            w += (size_t)E_LOCAL * 4;
  int* csr2 = (int*)w;            w += (size_t)E_GLOBAL * 4;
  int* bcur = (int*)w;            w += 2 * NB * 4;   // + gcur[2] right after
  int* gcur = (int*)w;            w += 2 * 4;
  uint2* bb1 = (uint2*)w;         w += (size_t)NB * BCAP1 * 8;
  uint2* bb2 = (uint2*)w;         w += (size_t)NB * BCAP2 * 8;

  // zero bucket counters + segment cursors (contiguous)
  hipMemsetAsync(bcur, 0, (2 * NB + 2) * sizeof(int), stream);

  // K1: bucketize (470) + prep (1539)
  k1_prep_bucket<<<NWG_L + NWG_G + 1539, 256, 0, stream>>>(
      ei, gei, x, Wl1, Wr1, Wl2, Wr2, Wfc, bl1, br1, bl2, br2,
      xb, wt_all, wtfc, bias_all, bcur, bb1, bb2);

  // K2: csrbuild (320, self-reserving) + fused transform GEMM (3768)
  k2_csr_gemm<<<2 * NB + 24 * 157, 256, 0, stream>>>(
      bcur, gcur, bb1, bb2, csr1, csr2, st1, en1, st2, en2,
      xb, wt_all, bias_all, feat);

  // K3: cooperative aggregation, both layers
  aggregate2<<<2 * N_NODES, 256, 0, stream>>>(
      feat, att1, att2, csr1, st1, en1, b1, csr2, st2, en2, b2, hb);

  // K4: final FC
  k4_fc<<<2 * 157, 256, 0, stream>>>(hb, wtfc, bfc, out);
}